// Round 5
// baseline (88.926 us; speedup 1.0000x reference)
//
#include <hip/hip_runtime.h>

#define EPS 1e-8f

constexpr int NROWS = 1024;
constexpr int K     = 256;
constexpr int NQ    = K / 4;   // 64 float4 "quads" per row
constexpr int BR    = 32;      // block tile rows (x)
constexpr int BC    = 64;      // block tile cols (y)

// ---------------- Kernel A: row sums ----------------
__global__ __launch_bounds__(256) void rowsum_kernel(const float* __restrict__ x,
                                                     const float* __restrict__ y,
                                                     float* __restrict__ sums) {
    const int wave = threadIdx.x >> 6;
    const int lane = threadIdx.x & 63;
    const int row  = blockIdx.x * 4 + wave;   // 0..2047
    const float* src = (row < NROWS) ? (x + (size_t)row * K)
                                     : (y + (size_t)(row - NROWS) * K);
    float4 v = ((const float4*)src)[lane];
    float s = (v.x + v.y) + (v.z + v.w);
    #pragma unroll
    for (int off = 32; off > 0; off >>= 1) s += __shfl_down(s, off);
    if (lane == 0) sums[row] = s;
}

// ---------------- Kernel B: scalar-operand Ruzicka ----------------
// Grid (16, 32), 256 threads (4 waves), 2 blocks/CU.
// Lane l  -> output column colBase + l  (y row l, per-lane, staged in LDS).
// Wave w  -> output rows rowBase + 8w .. 8w+7 (x rows, wave-uniform -> s_load).
// Inner loop: v_min_f32(sgpr, vgpr) + v_add_f32. One ds_read_b128 per lane
// per 4k. No barriers after the single staging sync.
// LDS: y-tile 64 rows x 64 quads, quad q of row j stored at q ^ (j & 7)
// (reads/writes hit the 8-phase b128 floor, no extra conflicts).
__global__ __launch_bounds__(256, 2) void ruzicka_kernel(const float* __restrict__ x,
                                                         const float* __restrict__ y,
                                                         const float* __restrict__ sums,
                                                         float* __restrict__ out) {
    __shared__ float4 ylds[BC * NQ];   // 64 KB

    const int tid  = threadIdx.x;
    const int lane = tid & 63;
    const int wv   = __builtin_amdgcn_readfirstlane(tid >> 6);  // wave-uniform
    const int colBase = blockIdx.x * BC;
    const int rowBase = blockIdx.y * BR;

    // ---- stage y-tile: wave wv handles y rows j = 4i + wv; lane = quad ----
    #pragma unroll
    for (int i = 0; i < 16; ++i) {
        const int j = 4 * i + wv;
        const float4 v = *(const float4*)&y[(size_t)(colBase + j) * K + lane * 4];
        ylds[j * NQ + (lane ^ (j & 7))] = v;
    }
    __syncthreads();

    const float* xw = x + (size_t)(rowBase + wv * 8) * K;   // uniform base
    const int swz = lane & 7;

    float acc[8];
    #pragma unroll
    for (int r = 0; r < 8; ++r) acc[r] = 0.0f;

    #pragma unroll 4
    for (int q = 0; q < NQ; ++q) {
        const float4 yv = ylds[lane * NQ + (q ^ swz)];   // per-lane y quad
        #pragma unroll
        for (int r = 0; r < 8; ++r) {
            const float4 xv = *(const float4*)&xw[r * K + q * 4];  // uniform -> s_load
            acc[r] += (fminf(xv.x, yv.x) + fminf(xv.y, yv.y))
                    + (fminf(xv.z, yv.z) + fminf(xv.w, yv.w));
        }
    }

    // ---- epilogue: coalesced dword stores, lane = column ----
    const float syl = sums[NROWS + colBase + lane];   // per-lane, coalesced
    #pragma unroll
    for (int r = 0; r < 8; ++r) {
        const int row = rowBase + wv * 8 + r;
        const float sx = sums[row];                   // uniform -> s_load
        const float n  = acc[r];
        out[(size_t)row * NROWS + colBase + lane] = n / (sx + syl - n + EPS);
    }
}

extern "C" void kernel_launch(void* const* d_in, const int* in_sizes, int n_in,
                              void* d_out, int out_size, void* d_ws, size_t ws_size,
                              hipStream_t stream) {
    const float* x = (const float*)d_in[0];
    const float* y = (const float*)d_in[1];
    float* out  = (float*)d_out;
    float* sums = (float*)d_ws;   // 2048 floats: Sx[1024] then Sy[1024]

    rowsum_kernel<<<dim3(2048 / 4), dim3(256), 0, stream>>>(x, y, sums);
    ruzicka_kernel<<<dim3(NROWS / BC, NROWS / BR), dim3(256), 0, stream>>>(x, y, sums, out);
}